// Round 1
// baseline (283.257 us; speedup 1.0000x reference)
//
#include <hip/hip_runtime.h>
#include <math.h>

// ---------------- CQT constants (match reference) ----------------
#define NBINS    252
#define NFRAMES  456
#define HOPSZ    484
#define CENTER_  34682
#define SIGLEN   220500
// padded signal: 2*CENTER_ + SIGLEN = 289864, +2048 zero tail for tail-iter overread
#define PADLEN   291912
#define FT       8            // frames per block
#define NTILES   57           // 456 / 8
#define SRD      44100.0
#define FMIND    32.70319566257483

struct BinConst {
  double fos;        // freq / SR  (revolutions per sample)
  double invL;       // 1 / L
  float  inv_norm;   // 1 / (win_sum * sqrt(L))
  int    T;          // window half-width: taps t in [-T, T]
  // modulation rotation constants: phase steps of 1,2,3,1024 samples
  float  mc0, ms0, mc1, ms1, mc2, ms2, mcJ, msJ;
  // window rotation constants: same steps at frequency 1/L
  float  wc0, ws0, wc1, ws1, wc2, ws2, wcJ, wsJ;
};

// ---------------- pad signal into workspace ----------------
__global__ __launch_bounds__(256) void pad_kernel(const float* __restrict__ sig,
                                                  float* __restrict__ pad) {
  int i = blockIdx.x * blockDim.x + threadIdx.x;
  if (i < PADLEN) {
    float v = 0.0f;
    int s = i - CENTER_;
    if (s >= 0 && s < SIGLEN) v = sig[s];
    pad[i] = v;
  }
}

// ---------------- per-bin constants (double precision, runs once per call) ----------------
__global__ __launch_bounds__(256) void bins_kernel(BinConst* __restrict__ bc) {
  int b = blockIdx.x * blockDim.x + threadIdx.x;
  if (b >= NBINS) return;
  const double PI  = 3.14159265358979323846;
  const double TWO_PI = 6.28318530717958647692;
  double freq = FMIND * exp2((double)b / 36.0);
  double fos  = freq / SRD;
  double Q    = 1.0 / (exp2(1.0 / 36.0) - 1.0);
  double L    = Q * SRD / freq;
  int    T    = (int)(L * 0.5);          // floor; L/2 is never an exact integer here
  double N    = (double)(2 * T + 1);
  // win_sum = sum_{t=-T..T} 0.5*(1+cos(2*pi*t/L))
  //         = 0.5*N + 0.5*sin(N*pi/L)/sin(pi/L);  sin(N*pi/L) = -sin(pi*(N-L)/L)
  double x1 = PI * (N - L) / L;          // small
  double x2 = PI / L;                    // small
  double win_sum = 0.5 * N - 0.5 * (sin(x1) / sin(x2));

  BinConst c;
  c.fos = fos;
  c.invL = 1.0 / L;
  c.inv_norm = (float)(1.0 / (win_sum * sqrt(L)));
  c.T = T;

  double r;
  r = fos * 1.0;    r -= floor(r); c.mc0 = (float)cos(TWO_PI * r); c.ms0 = (float)sin(TWO_PI * r);
  r = fos * 2.0;    r -= floor(r); c.mc1 = (float)cos(TWO_PI * r); c.ms1 = (float)sin(TWO_PI * r);
  r = fos * 3.0;    r -= floor(r); c.mc2 = (float)cos(TWO_PI * r); c.ms2 = (float)sin(TWO_PI * r);
  r = fos * 1024.0; r -= floor(r); c.mcJ = (float)cos(TWO_PI * r); c.msJ = (float)sin(TWO_PI * r);

  r = 1.0 / L;      c.wc0 = (float)cos(TWO_PI * r); c.ws0 = (float)sin(TWO_PI * r);
  r = 2.0 / L;      c.wc1 = (float)cos(TWO_PI * r); c.ws1 = (float)sin(TWO_PI * r);
  r = 3.0 / L;      c.wc2 = (float)cos(TWO_PI * r); c.ws2 = (float)sin(TWO_PI * r);
  r = 1024.0 / L;   r -= floor(r); c.wcJ = (float)cos(TWO_PI * r); c.wsJ = (float)sin(TWO_PI * r);

  bc[b] = c;
}

// ---------------- main CQT kernel ----------------
// grid: (NTILES, NBINS); block: 256 threads (4 waves).
// Each block: one bin b, frames [tile*FT, tile*FT+FT).
// Lane l handles taps t0+4l .. t0+4l+3, block-strided by 1024 taps per iteration.
// Tap values (Hann * cos/sin modulation) generated by f32 complex rotation;
// per-bin 1/norm folded into the epilogue.
__global__ __launch_bounds__(256) void cqt_kernel(const float* __restrict__ pad,
                                                  const BinConst* __restrict__ bct,
                                                  float* __restrict__ out) {
  const int b    = blockIdx.y;
  const int f0   = blockIdx.x * FT;
  const BinConst c = bct[b];

  const int Tb    = c.T;
  const int delta = (CENTER_ - Tb) & 3;      // round start down so j0 % 4 == 0 (16B-aligned float4)
  const int l     = threadIdx.x;
  const int t0    = -(Tb + delta) + 4 * l;   // this lane's first tap (centered coords)
  const int total = 2 * Tb + 1 + delta;
  const int iters = (total + 1023) >> 10;

  // --- init rotation states at tap t0 ---
  double rv = c.fos * (double)t0;  rv -= floor(rv);
  float am = (float)rv * 6.283185307179586f;
  float sm, cm; __sincosf(am, &sm, &cm);     // modulation cos/sin at t0

  double rw = c.invL * (double)t0; rw -= floor(rw);
  float aw = (float)rw * 6.283185307179586f;
  float sw, cw; __sincosf(aw, &sw, &cw);     // window-cos rotation state at t0

  float accr[FT], acci[FT];
#pragma unroll
  for (int q = 0; q < FT; ++q) { accr[q] = 0.0f; acci[q] = 0.0f; }

  const int j0 = CENTER_ + t0;               // multiple of 4 by construction
  const float* pp = pad + (f0 * HOPSZ + j0); // 16B-aligned (HOPSZ*4 % 16 == 0)

  int t = t0;
  for (int k = 0; k < iters; ++k) {
    // derive the 4 consecutive taps from the base rotation state
    float w0 = fmaf(0.5f, cw, 0.5f);

    float c1  = cm * c.mc0 - sm * c.ms0;
    float s1  = sm * c.mc0 + cm * c.ms0;
    float cw1 = cw * c.wc0 - sw * c.ws0;
    float w1  = fmaf(0.5f, cw1, 0.5f);

    float c2  = cm * c.mc1 - sm * c.ms1;
    float s2  = sm * c.mc1 + cm * c.ms1;
    float cw2 = cw * c.wc1 - sw * c.ws1;
    float w2  = fmaf(0.5f, cw2, 0.5f);

    float c3  = cm * c.mc2 - sm * c.ms2;
    float s3  = sm * c.mc2 + cm * c.ms2;
    float cw3 = cw * c.wc2 - sw * c.ws2;
    float w3  = fmaf(0.5f, cw3, 0.5f);

    if (k == 0 || k == iters - 1) {          // head/tail: zero weights outside [-Tb, Tb]
      w0 = ((unsigned)(t + 0 + Tb) <= (unsigned)(2 * Tb)) ? w0 : 0.0f;
      w1 = ((unsigned)(t + 1 + Tb) <= (unsigned)(2 * Tb)) ? w1 : 0.0f;
      w2 = ((unsigned)(t + 2 + Tb) <= (unsigned)(2 * Tb)) ? w2 : 0.0f;
      w3 = ((unsigned)(t + 3 + Tb) <= (unsigned)(2 * Tb)) ? w3 : 0.0f;
    }

    const float kr0 = w0 * cm, ki0 = w0 * sm;
    const float kr1 = w1 * c1, ki1 = w1 * s1;
    const float kr2 = w2 * c2, ki2 = w2 * s2;
    const float kr3 = w3 * c3, ki3 = w3 * s3;

#pragma unroll
    for (int q = 0; q < FT; ++q) {
      const float4 x = *reinterpret_cast<const float4*>(pp + q * HOPSZ);
      accr[q] = fmaf(x.x, kr0, accr[q]);  acci[q] = fmaf(x.x, ki0, acci[q]);
      accr[q] = fmaf(x.y, kr1, accr[q]);  acci[q] = fmaf(x.y, ki1, acci[q]);
      accr[q] = fmaf(x.z, kr2, accr[q]);  acci[q] = fmaf(x.z, ki2, acci[q]);
      accr[q] = fmaf(x.w, kr3, accr[q]);  acci[q] = fmaf(x.w, ki3, acci[q]);
    }

    // advance base state by 1024 taps
    float cn  = cm * c.mcJ - sm * c.msJ;
    float sn  = sm * c.mcJ + cm * c.msJ;
    cm = cn; sm = sn;
    float cwn = cw * c.wcJ - sw * c.wsJ;
    float swn = sw * c.wcJ + cw * c.wsJ;
    cw = cwn; sw = swn;

    pp += 1024;
    t  += 1024;
  }

  // --- reduce 64 lanes per wave ---
#pragma unroll
  for (int q = 0; q < FT; ++q) {
    float r = accr[q], i2 = acci[q];
    for (int m = 1; m < 64; m <<= 1) {
      r  += __shfl_xor(r, m, 64);
      i2 += __shfl_xor(i2, m, 64);
    }
    accr[q] = r; acci[q] = i2;
  }

  // --- combine 4 waves via LDS ---
  __shared__ float ldsr[4][FT];
  __shared__ float ldsi[4][FT];
  const int wave = threadIdx.x >> 6;
  if ((threadIdx.x & 63) == 0) {
#pragma unroll
    for (int q = 0; q < FT; ++q) { ldsr[wave][q] = accr[q]; ldsi[wave][q] = acci[q]; }
  }
  __syncthreads();
  if (threadIdx.x < FT) {
    const int q = threadIdx.x;
    float r  = ldsr[0][q] + ldsr[1][q] + ldsr[2][q] + ldsr[3][q];
    float i2 = ldsi[0][q] + ldsi[1][q] + ldsi[2][q] + ldsi[3][q];
    out[b * NFRAMES + f0 + q] = c.inv_norm * sqrtf(r * r + i2 * i2);
  }
}

// ---------------- launch ----------------
extern "C" void kernel_launch(void* const* d_in, const int* in_sizes, int n_in,
                              void* d_out, int out_size, void* d_ws, size_t ws_size,
                              hipStream_t stream) {
  const float* sig = (const float*)d_in[0];
  float* out = (float*)d_out;

  // workspace layout: [0, PADLEN) floats padded signal; then BinConst table (8B aligned)
  float* pad = (float*)d_ws;
  BinConst* bct = (BinConst*)((char*)d_ws + (size_t)PADLEN * sizeof(float));

  pad_kernel<<<(PADLEN + 255) / 256, 256, 0, stream>>>(sig, pad);
  bins_kernel<<<1, 256, 0, stream>>>(bct);
  cqt_kernel<<<dim3(NTILES, NBINS), 256, 0, stream>>>(pad, bct, out);
}

// Round 2
// 126.714 us; speedup vs baseline: 2.2354x; 2.2354x over previous
//
#include <hip/hip_runtime.h>
#include <hip/hip_bf16.h>
#include <math.h>

// ---------------- CQT constants ----------------
#define NBINS    252
#define NFRAMES  456
#define HOPSZ    484
#define SIGLEN   220500
#define PADOFF   34688          // bf16 signal padding offset (mult of 4)
#define XBF_ELEMS 317440        // padded bf16 signal length (covers all reads, zero-filled)
#define SRD      44100.0
#define FMIND    32.70319566257483
#define TWO_PI_D 6.283185307179586476925287
#define MAXCH    288
#define SC       32             // K-steps (x32 taps) per chunk
#define CHUNK_BYTES (SC*2048)   // 65536 B  per chunk of bank
#define CHUNK_ELEMS (SC*1024)   // 32768 ushort per chunk

typedef unsigned short ushort_t;
typedef __attribute__((ext_vector_type(8))) short bf16x8;
typedef __attribute__((ext_vector_type(4))) float f32x4;

struct ChunkTab { int2 e[MAXCH]; };   // .x = group, .y = jadj (tap offset of chunk start)

// ---------------- bf16 padded signal ----------------
__global__ __launch_bounds__(256) void pad_bf16(const float* __restrict__ sig,
                                                ushort_t* __restrict__ xbf) {
  int i = blockIdx.x * 256 + threadIdx.x;
  if (i < XBF_ELEMS) {
    int s = i - PADOFF;
    float v = (s >= 0 && s < SIGLEN) ? sig[s] : 0.0f;
    __hip_bfloat16 h = __float2bfloat16(v);
    xbf[i] = *reinterpret_cast<ushort_t*>(&h);
  }
}

// ---------------- per-bin normalization (1 / (win_sum * sqrt(L))) ----------------
__global__ __launch_bounds__(256) void norm_kernel(float* __restrict__ nrm) {
  int b = blockIdx.x * 256 + threadIdx.x;
  if (b >= NBINS) return;
  const double PI = 3.14159265358979323846;
  double freq = FMIND * exp2((double)b / 36.0);
  double Q = 1.0 / (exp2(1.0 / 36.0) - 1.0);
  double L = Q * SRD / freq;
  int T = (int)(L * 0.5);
  double N = (double)(2 * T + 1);
  double win_sum = 0.5 * N - 0.5 * (sin(PI * (N - L) / L) / sin(PI / L));
  nrm[b] = (float)(1.0 / (win_sum * sqrt(L)));
}

// ---------------- kernel-bank generation, pre-swizzled to B-fragment layout ----------
// bank[c][ks][frag][lane][j] bf16 : frag0 = kr (cos), frag1 = ki (sin), un-normalized.
// lane -> (bin = 16g + (lane&15), k_local = (lane>>4)*8 + j), t = jadj + ks*32 + k_local.
__global__ __launch_bounds__(256) void gen_bank(ushort_t* __restrict__ bank, ChunkTab tab) {
  int c = blockIdx.y;
  int e = blockIdx.x * 256 + threadIdx.x;   // 0..4095
  int ks = e >> 7;
  int rem = e & 127;
  int frag = (rem >> 6) & 1;
  int lane = rem & 63;
  int bl = lane & 15, kb = lane >> 4;
  int g = tab.e[c].x, jadj = tab.e[c].y;
  int b = g * 16 + bl;
  int t0 = jadj + ks * 32 + kb * 8;

  ushort_t res[8];
#pragma unroll
  for (int j = 0; j < 8; ++j) res[j] = 0;

  if (b < NBINS) {
    double freq = FMIND * exp2((double)b / 36.0);
    double fos = freq / SRD;
    double Q = 1.0 / (exp2(1.0 / 36.0) - 1.0);
    double L = Q * SRD / freq;
    int T = (int)(L * 0.5);
    if (t0 + 7 >= -T && t0 <= T) {
      double rv = fos * (double)t0; rv -= floor(rv);
      float ang0 = (float)(rv * TWO_PI_D);
      float dang = (float)(fos * TWO_PI_D);
      float invL = (float)(1.0 / L);
#pragma unroll
      for (int j = 0; j < 8; ++j) {
        int tt = t0 + j;
        if (tt >= -T && tt <= T) {
          float win = 0.5f + 0.5f * __cosf(6.2831853f * ((float)tt * invL));
          float s, cc;
          __sincosf(ang0 + (float)j * dang, &s, &cc);
          float val = win * (frag ? s : cc);
          __hip_bfloat16 h = __float2bfloat16(val);
          res[j] = *reinterpret_cast<ushort_t*>(&h);
        }
      }
    }
  }
  union { ushort_t u[8]; uint4 v; } pk;
#pragma unroll
  for (int j = 0; j < 8; ++j) pk.u[j] = res[j];
  *reinterpret_cast<uint4*>(bank + (size_t)c * CHUNK_ELEMS + ks * 1024 + frag * 512 + lane * 8) = pk.v;
}

// ---------------- zero the accumulator ----------------
__global__ __launch_bounds__(256) void zero_accum(float* __restrict__ acc) {
  acc[blockIdx.x * 256 + threadIdx.x] = 0.0f;   // grid sized exactly
}

// ---------------- main block-sparse MFMA GEMM ----------------
// grid (4 frame-supertiles, nch chunks), 256 thr = 4 waves.
// wave w: frames fbase = st*128 + w*32 (two 16-row A tiles), 32 cols (16 kr + 16 ki).
__global__ __launch_bounds__(256) void cqt_mfma(const ushort_t* __restrict__ xbf,
                                                const ushort_t* __restrict__ bank,
                                                float* __restrict__ accum,
                                                ChunkTab tab) {
  const int tid = threadIdx.x;
  const int lane = tid & 63;
  const int w = tid >> 6;
  const int c = blockIdx.y;
  const int g = tab.e[c].x, jadj = tab.e[c].y;
  const int bl = lane & 15, kb = lane >> 4;
  const int fbase = blockIdx.x * 128 + w * 32;

  // A: row m = lane&15 -> frame fbase+m ; k chunk kb*8 (8B-aligned: all terms %4==0 in elems)
  const ushort_t* pA0 = xbf + (PADOFF + (fbase + bl) * HOPSZ + jadj + kb * 8);
  const ushort_t* pA1 = pA0 + 16 * HOPSZ;
  const ushort_t* pB  = bank + (size_t)c * CHUNK_ELEMS + lane * 8;

  f32x4 ar0 = {0.f, 0.f, 0.f, 0.f};
  f32x4 ai0 = ar0, ar1 = ar0, ai1 = ar0;

#pragma unroll 4
  for (int ks = 0; ks < SC; ++ks) {
    union { uint2 q[2]; bf16x8 v; } a0, a1;
    a0.q[0] = *reinterpret_cast<const uint2*>(pA0 + ks * 32);
    a0.q[1] = *reinterpret_cast<const uint2*>(pA0 + ks * 32 + 4);
    a1.q[0] = *reinterpret_cast<const uint2*>(pA1 + ks * 32);
    a1.q[1] = *reinterpret_cast<const uint2*>(pA1 + ks * 32 + 4);
    union { uint4 q; bf16x8 v; } bk, bi;
    bk.q = *reinterpret_cast<const uint4*>(pB + ks * 1024);
    bi.q = *reinterpret_cast<const uint4*>(pB + ks * 1024 + 512);
    ar0 = __builtin_amdgcn_mfma_f32_16x16x32_bf16(a0.v, bk.v, ar0, 0, 0, 0);
    ai0 = __builtin_amdgcn_mfma_f32_16x16x32_bf16(a0.v, bi.v, ai0, 0, 0, 0);
    ar1 = __builtin_amdgcn_mfma_f32_16x16x32_bf16(a1.v, bk.v, ar1, 0, 0, 0);
    ai1 = __builtin_amdgcn_mfma_f32_16x16x32_bf16(a1.v, bi.v, ai1, 0, 0, 0);
  }

  // C/D: col = lane&15 (bin-in-group), row = (lane>>4)*4 + reg  [m89-verified]
  float* ap = accum + ((size_t)(g * 512 + fbase) * 16 + bl) * 2;
  const int row = kb * 4;
#pragma unroll
  for (int r = 0; r < 4; ++r) {
    atomicAdd(ap + (size_t)(row + r) * 32,            ar0[r]);
    atomicAdd(ap + (size_t)(row + r) * 32 + 1,        ai0[r]);
    atomicAdd(ap + (size_t)(row + r + 16) * 32,       ar1[r]);
    atomicAdd(ap + (size_t)(row + r + 16) * 32 + 1,   ai1[r]);
  }
}

// ---------------- finalize: magnitude + per-bin norm ----------------
__global__ __launch_bounds__(256) void fin_kernel(const float* __restrict__ accum,
                                                  const float* __restrict__ nrm,
                                                  float* __restrict__ out) {
  int id = blockIdx.x * 256 + threadIdx.x;
  if (id >= NBINS * NFRAMES) return;
  int b = id / NFRAMES;
  int f = id - b * NFRAMES;
  int g = b >> 4, bl = b & 15;
  size_t ai = ((size_t)(g * 512 + f) * 16 + bl) * 2;
  float cr = accum[ai], ci = accum[ai + 1];
  out[id] = nrm[b] * sqrtf(cr * cr + ci * ci);
}

// ---------------- launch ----------------
extern "C" void kernel_launch(void* const* d_in, const int* in_sizes, int n_in,
                              void* d_out, int out_size, void* d_ws, size_t ws_size,
                              hipStream_t stream) {
  const float* sig = (const float*)d_in[0];
  float* out = (float*)d_out;
  char* ws = (char*)d_ws;

  // ws layout: xbf (634,880 B) | bank (288*65,536 B) | accum (1,048,576 B) | nrm (1,008 B)
  ushort_t* xbf  = (ushort_t*)ws;
  ushort_t* bank = (ushort_t*)(ws + 634880);
  float* accum   = (float*)(ws + 634880 + (size_t)MAXCH * CHUNK_BYTES);
  float* nrm     = (float*)(ws + 634880 + (size_t)MAXCH * CHUNK_BYTES + 1048576);

  // host-side chunk table (pure arithmetic, identical every call)
  ChunkTab tab;
  int nch = 0;
  const double Q = 1.0 / (exp2(1.0 / 36.0) - 1.0);
  for (int gq = 0; gq < 16; ++gq) {
    double freq = FMIND * exp2((double)(16 * gq) / 36.0);
    double L = Q * SRD / freq;
    int T = (int)(L * 0.5);
    int r = (4 - (T & 3)) & 3;          // make tstart % 4 == 0 (8B-aligned A loads)
    int tstart = -(T + r);
    int ntaps = 2 * T + 1 + r;
    int nsteps = (ntaps + 31) / 32;
    for (int ks0 = 0; ks0 < nsteps && nch < MAXCH; ks0 += SC) {
      tab.e[nch].x = gq;
      tab.e[nch].y = tstart + ks0 * 32;
      ++nch;
    }
  }
  for (int i = nch; i < MAXCH; ++i) { tab.e[i].x = 0; tab.e[i].y = 0; }

  pad_bf16<<<(XBF_ELEMS + 255) / 256, 256, 0, stream>>>(sig, xbf);
  norm_kernel<<<1, 256, 0, stream>>>(nrm);
  gen_bank<<<dim3(16, nch), 256, 0, stream>>>(bank, tab);
  zero_accum<<<1024, 256, 0, stream>>>(accum);   // 16*512*16*2 = 262,144 floats exactly
  cqt_mfma<<<dim3(4, nch), 256, 0, stream>>>(xbf, bank, accum, tab);
  fin_kernel<<<(NBINS * NFRAMES + 255) / 256, 256, 0, stream>>>(accum, nrm, out);
}